// Round 8
// baseline (347.632 us; speedup 1.0000x reference)
//
#include <hip/hip_runtime.h>
#include <hip/hip_bf16.h>

#define DIM 128
#define NWORD 100000
#define NTOPIC 10000
#define NDOC 50000
#define NOUT (NWORD + NTOPIC + NDOC)

#define E_WW 200000
#define E_WT 100000
#define E_WD 150000
#define E_TD 100000
#define E_TT 50000
#define E_TOT 600000

// per-(relation,dst) counter slot bases in the concatenated slot space
#define B_WW 0
#define B_WT 100000
#define B_TT 110000
#define B_WD 120000
#define B_TD 170000
#define NSLOT 220000

#define NBLK_CSR 215   // ceil(220000/1024); <= 256 CUs -> all co-resident

#define NBW 466   // transform blocks for word
#define NBT 46    // transform blocks for topic  (NBW+NBT = 512 = resident capacity)

typedef __attribute__((ext_vector_type(8))) short bf16x8;
typedef __attribute__((ext_vector_type(8))) unsigned short u16x8;
typedef __attribute__((ext_vector_type(4))) float f32x4;

__device__ __forceinline__ unsigned short f2bf(float f) {
    __hip_bfloat16 h = __float2bfloat16(f);
    return __builtin_bit_cast(unsigned short, h);
}
__device__ __forceinline__ float b2f(unsigned short u) {
    return __builtin_bit_cast(float, (unsigned)u << 16);
}

#define AGENT __HIP_MEMORY_SCOPE_AGENT
__device__ __forceinline__ unsigned aload(const unsigned* p) {
    return __hip_atomic_load(p, __ATOMIC_RELAXED, AGENT);
}
__device__ __forceinline__ void astore(unsigned* p, unsigned v) {
    __hip_atomic_store(p, v, __ATOMIC_RELAXED, AGENT);
}

// grid-wide spin barrier; requires all blocks co-resident (grid <= 256 CUs)
__device__ __forceinline__ void gbar(unsigned* bar, unsigned target) {
    __syncthreads();
    if (threadIdx.x == 0) {
        __hip_atomic_fetch_add(bar, 1u, __ATOMIC_ACQ_REL, AGENT);
        while (__hip_atomic_load(bar, __ATOMIC_ACQUIRE, AGENT) < target)
            __builtin_amdgcn_s_sleep(4);
    }
    __syncthreads();
}

// ---------------------------------------------------------------------------
// prep1 = compose stage 1 + zero(cnt, bar).
//   blocks 0..127   : A[r][j]     = sum_m W_wd[r,m] * W_wt[m,j]
//   blocks 128..255 : Wbf_t[j][k] = bf16( sum_m W_tt[j,m] * W_td[m,k] )
//   block 256       : tmpb[j] = W_wt@b_ww + b_wt ; block 257: c_t = W_tt@b_td + b_tt
// ---------------------------------------------------------------------------
__global__ __launch_bounds__(128) void prep1(
    const float* __restrict__ W_ww, const float* __restrict__ b_ww,
    const float* __restrict__ W_wt, const float* __restrict__ b_wt,
    const float* __restrict__ W_wd, const float* __restrict__ b_wd,
    const float* __restrict__ W_td, const float* __restrict__ b_td,
    const float* __restrict__ W_tt, const float* __restrict__ b_tt,
    float* __restrict__ A, unsigned short* __restrict__ Wbf_t,
    float* __restrict__ tmpb, float* __restrict__ c_t, unsigned* __restrict__ zbase)
{
    int b = blockIdx.x, j = threadIdx.x;
    for (int i = b * 128 + j; i < NSLOT + 16; i += gridDim.x * 128) zbase[i] = 0u;

    if (b < 128) {
        const float* wr = &W_wd[b * 128];
        float s0 = 0.f, s1 = 0.f, s2 = 0.f, s3 = 0.f;
        for (int m = 0; m < 128; m += 4) {
            s0 = fmaf(wr[m + 0], W_wt[(m + 0) * 128 + j], s0);
            s1 = fmaf(wr[m + 1], W_wt[(m + 1) * 128 + j], s1);
            s2 = fmaf(wr[m + 2], W_wt[(m + 2) * 128 + j], s2);
            s3 = fmaf(wr[m + 3], W_wt[(m + 3) * 128 + j], s3);
        }
        A[b * 128 + j] = (s0 + s1) + (s2 + s3);
    } else if (b < 256) {
        int k = b - 128;
        const float* wr = &W_tt[j * 128];
        float s0 = 0.f, s1 = 0.f, s2 = 0.f, s3 = 0.f;
        for (int m = 0; m < 128; m += 4) {
            s0 = fmaf(wr[m + 0], W_td[(m + 0) * 128 + k], s0);
            s1 = fmaf(wr[m + 1], W_td[(m + 1) * 128 + k], s1);
            s2 = fmaf(wr[m + 2], W_td[(m + 2) * 128 + k], s2);
            s3 = fmaf(wr[m + 3], W_td[(m + 3) * 128 + k], s3);
        }
        Wbf_t[j * 128 + k] = f2bf((s0 + s1) + (s2 + s3));
    } else if (b == 256) {
        float s = b_wt[j];
        for (int m = 0; m < 128; ++m) s = fmaf(W_wt[j * 128 + m], b_ww[m], s);
        tmpb[j] = s;
    } else {
        float s = b_tt[j];
        for (int m = 0; m < 128; ++m) s = fmaf(W_tt[j * 128 + m], b_td[m], s);
        c_t[j] = s;
    }
}

// ---------------------------------------------------------------------------
// edge decode helpers (concatenated edge space)
// ---------------------------------------------------------------------------
__device__ __forceinline__ int edge_slot(
    int g, const int* __restrict__ dw, const int* __restrict__ dt,
    const int* __restrict__ dd, const int* __restrict__ dtd, const int* __restrict__ dtt)
{
    if (g < E_WW)                           return B_WW + dw[g];
    if (g < E_WW + E_WT)                    return B_WT + dt[g - E_WW];
    if (g < E_WW + E_WT + E_WD)             return B_WD + dd[g - E_WW - E_WT];
    if (g < E_WW + E_WT + E_WD + E_TD)      return B_TD + dtd[g - E_WW - E_WT - E_WD];
    return B_TT + dtt[g - E_WW - E_WT - E_WD - E_TD];
}

// ---------------------------------------------------------------------------
// csr_build: ONE kernel, 215 co-resident blocks, 3 grid barriers.
//   phase 0: compose stage 2 (blocks 0..64) + rank_count (all blocks)
//   phase 1: per-block slot sums -> bsum
//   phase 2: every block computes its own prefix from bsum; writes offs
//   phase 3: place edge records (atomic-free)
// All cross-phase arrays accessed with agent-scope atomics (XCD L2 coherence).
// ---------------------------------------------------------------------------
__global__ __launch_bounds__(256) void csr_build(
    const float* __restrict__ W_ww, const float* __restrict__ W_wd,
    const float* __restrict__ b_wd, const float* __restrict__ A,
    const float* __restrict__ tmpb,
    unsigned short* __restrict__ Wbf_w, float* __restrict__ c_w,
    const int* __restrict__ dst_ww, const int* __restrict__ dst_wt,
    const int* __restrict__ dst_wd, const int* __restrict__ dst_td,
    const int* __restrict__ dst_tt,
    const int* __restrict__ src_ww, const int* __restrict__ src_wt,
    const int* __restrict__ src_wd, const int* __restrict__ src_td,
    const int* __restrict__ src_tt,
    const float* __restrict__ ew_ww, const float* __restrict__ ew_wt,
    const float* __restrict__ ew_wd, const float* __restrict__ ew_td,
    const float* __restrict__ ew_tt,
    unsigned* __restrict__ cnt, unsigned* __restrict__ rank,
    unsigned* __restrict__ offs, unsigned* __restrict__ bsum,
    unsigned* __restrict__ bar, uint2* __restrict__ se)
{
    __shared__ unsigned sh[256];
    const int b = blockIdx.x, t = threadIdx.x;

    // ---- phase 0a: compose stage 2 ----
    if (b < 64) {
        int k = b * 2 + (t >> 7), j = t & 127;
        const float* ar = &A[j * 128];
        float s0 = 0.f, s1 = 0.f, s2 = 0.f, s3 = 0.f;
        for (int m = 0; m < 128; m += 4) {
            s0 = fmaf(ar[m + 0], W_ww[(m + 0) * 128 + k], s0);
            s1 = fmaf(ar[m + 1], W_ww[(m + 1) * 128 + k], s1);
            s2 = fmaf(ar[m + 2], W_ww[(m + 2) * 128 + k], s2);
            s3 = fmaf(ar[m + 3], W_ww[(m + 3) * 128 + k], s3);
        }
        Wbf_w[j * 128 + k] = f2bf((s0 + s1) + (s2 + s3));
    } else if (b == 64 && t < 128) {
        float s = b_wd[t];
        for (int m = 0; m < 128; ++m) s = fmaf(W_wd[t * 128 + m], tmpb[m], s);
        c_w[t] = s;
    }
    // ---- phase 0b: rank count ----
    for (int g = b * 256 + t; g < E_TOT; g += NBLK_CSR * 256) {
        int slotidx = edge_slot(g, dst_ww, dst_wt, dst_wd, dst_td, dst_tt);
        unsigned r = atomicAdd(&cnt[slotidx], 1u);
        astore(&rank[g], r);
    }
    gbar(bar, NBLK_CSR);

    // ---- phase 1: block-local sums over slots [b*1024, b*1024+1024) ----
    const int base = b * 1024 + t * 4;
    unsigned c0 = 0, c1 = 0, c2 = 0, c3 = 0;
    if (base + 0 < NSLOT) c0 = aload(&cnt[base + 0]);
    if (base + 1 < NSLOT) c1 = aload(&cnt[base + 1]);
    if (base + 2 < NSLOT) c2 = aload(&cnt[base + 2]);
    if (base + 3 < NSLOT) c3 = aload(&cnt[base + 3]);
    unsigned s = c0 + c1 + c2 + c3;
    sh[t] = s; __syncthreads();
    for (int o = 1; o < 256; o <<= 1) {
        unsigned x = (t >= o) ? sh[t - o] : 0u;
        __syncthreads();
        sh[t] += x;
        __syncthreads();
    }
    const unsigned excl = sh[t] - s;
    if (t == 0) astore(&bsum[b], sh[255]);
    gbar(bar, 2 * NBLK_CSR);

    // ---- phase 2: every block computes its own prefix; writes offs ----
    unsigned p = (t < b) ? aload(&bsum[t]) : 0u;   // t<b implies t<NBLK_CSR
    sh[t] = p; __syncthreads();
    for (int o = 128; o > 0; o >>= 1) { if (t < o) sh[t] += sh[t + o]; __syncthreads(); }
    unsigned run = sh[0] + excl;
    if (base + 0 < NSLOT) { astore(&offs[base + 0], run); run += c0; }
    if (base + 1 < NSLOT) { astore(&offs[base + 1], run); run += c1; }
    if (base + 2 < NSLOT) { astore(&offs[base + 2], run); run += c2; }
    if (base + 3 < NSLOT) { astore(&offs[base + 3], run); run += c3; }
    if (b == 0 && t == 0) astore(&offs[NSLOT], (unsigned)E_TOT);
    gbar(bar, 3 * NBLK_CSR);

    // ---- phase 3: place ----
    for (int g = b * 256 + t; g < E_TOT; g += NBLK_CSR * 256) {
        int slotidx, e; unsigned sv; float wv;
        if (g < E_WW)                           { e = g;                             slotidx = B_WW + dst_ww[e]; sv = src_ww[e]; wv = ew_ww[e]; }
        else if (g < E_WW + E_WT)               { e = g - E_WW;                      slotidx = B_WT + dst_wt[e]; sv = src_wt[e]; wv = ew_wt[e]; }
        else if (g < E_WW + E_WT + E_WD)        { e = g - E_WW - E_WT;               slotidx = B_WD + dst_wd[e]; sv = src_wd[e]; wv = ew_wd[e]; }
        else if (g < E_WW + E_WT + E_WD + E_TD) { e = g - E_WW - E_WT - E_WD;        slotidx = B_TD + dst_td[e]; sv = src_td[e]; wv = ew_td[e]; }
        else                                    { e = g - E_WW - E_WT - E_WD - E_TD; slotidx = B_TT + dst_tt[e]; sv = src_tt[e]; wv = ew_tt[e]; }
        unsigned r = aload(&rank[g]);
        unsigned o = aload(&offs[slotidx]);
        se[o + r] = make_uint2(sv, __builtin_bit_cast(unsigned, wv));
    }
}

// ---------------------------------------------------------------------------
// transform_mfma (merged word+topic): y_bf16[row] = bf16( x[row] @ Wc^T + c )
// One 16-row tile per wave, barrier-free; B-frags in registers; x staged bf16
// in per-wave 4KB LDS quarter with XOR swizzle; next tile's global loads
// prefetched into dead regs.
// ---------------------------------------------------------------------------
__global__ __launch_bounds__(256) void transform_mfma(
    const float* __restrict__ xw, const unsigned short* __restrict__ Wbf_w,
    const float* __restrict__ cw, unsigned short* __restrict__ yw, int ntw,
    const float* __restrict__ xt, const unsigned short* __restrict__ Wbf_t,
    const float* __restrict__ ct, unsigned short* __restrict__ yt, int ntt)
{
    __shared__ __attribute__((aligned(16))) unsigned short xs_all[4][16 * 128];
    const int tid = threadIdx.x;
    const int wid = tid >> 6, l = tid & 63;
    char* xs = (char*)xs_all[wid];
    const int l15 = l & 15, l4 = l >> 4;

    const bool isw = blockIdx.x < NBW;
    const float* x = isw ? xw : xt;
    const unsigned short* Wbf = isw ? Wbf_w : Wbf_t;
    const float* bias = isw ? cw : ct;
    unsigned short* y = isw ? yw : yt;
    const int nt = isw ? ntw : ntt;
    const int t0 = (isw ? blockIdx.x : blockIdx.x - NBW) * 4 + wid;
    const int tstr = (isw ? NBW : NBT) * 4;

    bf16x8 wf[8][4];
#pragma unroll
    for (int cg = 0; cg < 8; ++cg)
#pragma unroll
        for (int ki = 0; ki < 4; ++ki)
            wf[cg][ki] = *(const bf16x8*)&Wbf[(cg * 16 + l15) * 128 + ki * 32 + l4 * 8];

    float bj[8];
#pragma unroll
    for (int cg = 0; cg < 8; ++cg) bj[cg] = bias[cg * 16 + l15];

    const int row_s = l >> 2, ch = l & 3;   // staging: 4 lanes/row, 64B chunks

    float4 u[4], v[4];
    if (t0 < nt) {
        const float* xr = &x[((size_t)t0 * 16 + row_s) * 128 + ch * 32];
#pragma unroll
        for (int c = 0; c < 4; ++c) { u[c] = *(const float4*)(xr + c * 8); v[c] = *(const float4*)(xr + c * 8 + 4); }
    }

    for (int tile = t0; tile < nt; tile += tstr) {
#pragma unroll
        for (int c = 0; c < 4; ++c) {
            u16x8 p;
            p[0] = f2bf(u[c].x); p[1] = f2bf(u[c].y); p[2] = f2bf(u[c].z); p[3] = f2bf(u[c].w);
            p[4] = f2bf(v[c].x); p[5] = f2bf(v[c].y); p[6] = f2bf(v[c].z); p[7] = f2bf(v[c].w);
            int off = row_s * 256 + ((ch * 64 + c * 16) ^ ((row_s & 7) << 4));
            *(u16x8*)(xs + off) = p;
        }
        int nxt = tile + tstr;
        if (nxt < nt) {
            const float* xr = &x[((size_t)nxt * 16 + row_s) * 128 + ch * 32];
#pragma unroll
            for (int c = 0; c < 4; ++c) { u[c] = *(const float4*)(xr + c * 8); v[c] = *(const float4*)(xr + c * 8 + 4); }
        }

        f32x4 acc[8];
        const f32x4 zero = {0.f, 0.f, 0.f, 0.f};
#pragma unroll
        for (int cg = 0; cg < 8; ++cg) acc[cg] = zero;

#pragma unroll
        for (int ki = 0; ki < 4; ++ki) {
            int aoff = l15 * 256 + ((ki * 64 + l4 * 16) ^ ((l15 & 7) << 4));
            bf16x8 af = *(const bf16x8*)(xs + aoff);
#pragma unroll
            for (int cg = 0; cg < 8; ++cg)
                acc[cg] = __builtin_amdgcn_mfma_f32_16x16x32_bf16(af, wf[cg][ki], acc[cg], 0, 0, 0);
        }

        unsigned short* yr = &y[((size_t)tile * 16 + l4 * 4) * 128 + l15];
#pragma unroll
        for (int cg = 0; cg < 8; ++cg)
#pragma unroll
            for (int r = 0; r < 4; ++r)
                yr[r * 128 + cg * 16] = f2bf(acc[cg][r] + bj[cg]);
    }
}

// ---------------------------------------------------------------------------
// gather: 64 lanes per destination node. Half-wave h=lane>>5 takes one
// relation (topic/doc) or the even/odd edge interleave (word); halves are
// combined with one __shfl_xor(.,32). 4-deep edge pipelining, masked tails
// (se padded by 8 records).
// ---------------------------------------------------------------------------
__device__ __forceinline__ float4 seg_sum4(unsigned off, unsigned deg, unsigned j0,
                                           unsigned step,
                                           const uint2* __restrict__ se,
                                           const unsigned short* __restrict__ h, int d4)
{
    float ax = 0.f, ay = 0.f, az = 0.f, aw = 0.f;
    for (unsigned j = j0; j < deg; j += 4 * step) {
        uint2 r0 = se[off + j];
        uint2 r1 = se[off + j + step];
        uint2 r2 = se[off + j + 2 * step];
        uint2 r3 = se[off + j + 3 * step];
        unsigned s0 = r0.x;
        float    w0 = __builtin_bit_cast(float, r0.y);
        unsigned s1 = (j + step < deg) ? r1.x : 0u;
        float    w1 = (j + step < deg) ? __builtin_bit_cast(float, r1.y) : 0.f;
        unsigned s2 = (j + 2 * step < deg) ? r2.x : 0u;
        float    w2 = (j + 2 * step < deg) ? __builtin_bit_cast(float, r2.y) : 0.f;
        unsigned s3 = (j + 3 * step < deg) ? r3.x : 0u;
        float    w3 = (j + 3 * step < deg) ? __builtin_bit_cast(float, r3.y) : 0.f;
        ushort4 a0 = *(const ushort4*)&h[(size_t)s0 * 128 + d4];
        ushort4 a1 = *(const ushort4*)&h[(size_t)s1 * 128 + d4];
        ushort4 a2 = *(const ushort4*)&h[(size_t)s2 * 128 + d4];
        ushort4 a3 = *(const ushort4*)&h[(size_t)s3 * 128 + d4];
        ax = fmaf(b2f(a0.x), w0, ax); ay = fmaf(b2f(a0.y), w0, ay);
        az = fmaf(b2f(a0.z), w0, az); aw = fmaf(b2f(a0.w), w0, aw);
        ax = fmaf(b2f(a1.x), w1, ax); ay = fmaf(b2f(a1.y), w1, ay);
        az = fmaf(b2f(a1.z), w1, az); aw = fmaf(b2f(a1.w), w1, aw);
        ax = fmaf(b2f(a2.x), w2, ax); ay = fmaf(b2f(a2.y), w2, ay);
        az = fmaf(b2f(a2.z), w2, az); aw = fmaf(b2f(a2.w), w2, aw);
        ax = fmaf(b2f(a3.x), w3, ax); ay = fmaf(b2f(a3.y), w3, ay);
        az = fmaf(b2f(a3.z), w3, az); aw = fmaf(b2f(a3.w), w3, aw);
    }
    return float4{ax, ay, az, aw};
}

__global__ __launch_bounds__(256) void gather(
    const unsigned* __restrict__ offs, const uint2* __restrict__ se,
    const unsigned short* __restrict__ hw, const unsigned short* __restrict__ ht,
    float* __restrict__ out)
{
    int g = blockIdx.x * 256 + threadIdx.x;
    int n = g >> 6;
    int lane = g & 63;
    int h = lane >> 5, d4 = (lane & 31) << 2;
    if (n >= NOUT) return;
    float4 r;
    if (n < NWORD) {
        unsigned off = offs[n], deg = offs[n + 1] - off;
        float4 s = seg_sum4(off, deg, h, 2, se, hw, d4);   // even/odd interleave
        s.x += __shfl_xor(s.x, 32); s.y += __shfl_xor(s.y, 32);
        s.z += __shfl_xor(s.z, 32); s.w += __shfl_xor(s.w, 32);
        float inv = 1.0f / (float)(deg > 1u ? deg : 1u);
        r = float4{s.x * inv, s.y * inv, s.z * inv, s.w * inv};
    } else {
        int slot; const unsigned short* hx;
        if (n < NWORD + NTOPIC) {
            int i = n - NWORD;
            slot = (h == 0) ? (B_WT + i) : (B_TT + i);
            hx = (h == 0) ? hw : ht;
        } else {
            int i = n - NWORD - NTOPIC;
            slot = (h == 0) ? (B_WD + i) : (B_TD + i);
            hx = (h == 0) ? hw : ht;
        }
        unsigned off = offs[slot], deg = offs[slot + 1] - off;
        float4 s = seg_sum4(off, deg, 0, 1, se, hx, d4);
        float inv = 1.0f / (float)(deg > 1u ? deg : 1u);
        s.x *= inv; s.y *= inv; s.z *= inv; s.w *= inv;
        s.x += __shfl_xor(s.x, 32); s.y += __shfl_xor(s.y, 32);
        s.z += __shfl_xor(s.z, 32); s.w += __shfl_xor(s.w, 32);
        r = s;
    }
    if (h == 0) {
        r.x = fmaxf(r.x, 0.f); r.y = fmaxf(r.y, 0.f);
        r.z = fmaxf(r.z, 0.f); r.w = fmaxf(r.w, 0.f);
        *reinterpret_cast<float4*>(&out[(size_t)n * 128 + d4]) = r;
    }
}

extern "C" void kernel_launch(void* const* d_in, const int* in_sizes, int n_in,
                              void* d_out, int out_size, void* d_ws, size_t ws_size,
                              hipStream_t stream) {
    const float* h_word  = (const float*)d_in[0];
    const float* h_topic = (const float*)d_in[1];
    // d_in[2] = h_doc: unused (doc nodes only receive)
    const float* W_ww = (const float*)d_in[3];  const float* b_ww = (const float*)d_in[4];
    const float* W_wt = (const float*)d_in[5];  const float* b_wt = (const float*)d_in[6];
    const float* W_wd = (const float*)d_in[7];  const float* b_wd = (const float*)d_in[8];
    const float* W_td = (const float*)d_in[9];  const float* b_td = (const float*)d_in[10];
    const float* W_tt = (const float*)d_in[11]; const float* b_tt = (const float*)d_in[12];
    const int*   src_ww = (const int*)d_in[13]; const int* dst_ww = (const int*)d_in[14];
    const float* ew_ww  = (const float*)d_in[15];
    const int*   src_wt = (const int*)d_in[16]; const int* dst_wt = (const int*)d_in[17];
    const float* ew_wt  = (const float*)d_in[18];
    const int*   src_wd = (const int*)d_in[19]; const int* dst_wd = (const int*)d_in[20];
    const float* ew_wd  = (const float*)d_in[21];
    const int*   src_td = (const int*)d_in[22]; const int* dst_td = (const int*)d_in[23];
    const float* ew_td  = (const float*)d_in[24];
    const int*   src_tt = (const int*)d_in[25]; const int* dst_tt = (const int*)d_in[26];
    const float* ew_tt  = (const float*)d_in[27];

    float* out = (float*)d_out;

    // workspace layout
    unsigned short* hw_bf = (unsigned short*)d_ws;            // NWORD*128
    unsigned short* ht_bf = hw_bf + (size_t)NWORD * 128;      // NTOPIC*128
    unsigned short* Wbf_w = ht_bf + (size_t)NTOPIC * 128;     // 16384
    unsigned short* Wbf_t = Wbf_w + 16384;                    // 16384
    float* fbase = (float*)(Wbf_t + 16384);
    float* c_w   = fbase;                                     // 128
    float* c_t   = c_w + 128;                                 // 128
    float* Amat  = c_t + 128;                                 // 16384
    float* tmpb  = Amat + 16384;                              // 128
    uint2* se    = (uint2*)(tmpb + 128);                      // E_TOT + 8
    unsigned* cnt  = (unsigned*)(se + E_TOT + 8);             // NSLOT   } zeroed
    unsigned* bar  = cnt + NSLOT;                             // 16      } by prep1
    unsigned* offs = bar + 16;                                // NSLOT + 1
    unsigned* rank = offs + NSLOT + 1;                        // E_TOT
    unsigned* bsum = rank + E_TOT;                            // 256

    prep1<<<258, 128, 0, stream>>>(W_ww, b_ww, W_wt, b_wt, W_wd, b_wd, W_td, b_td,
                                   W_tt, b_tt, Amat, Wbf_t, tmpb, c_t, cnt);

    csr_build<<<NBLK_CSR, 256, 0, stream>>>(
        W_ww, W_wd, b_wd, Amat, tmpb, Wbf_w, c_w,
        dst_ww, dst_wt, dst_wd, dst_td, dst_tt,
        src_ww, src_wt, src_wd, src_td, src_tt,
        ew_ww, ew_wt, ew_wd, ew_td, ew_tt,
        cnt, rank, offs, bsum, bar, se);

    transform_mfma<<<NBW + NBT, 256, 0, stream>>>(
        h_word,  Wbf_w, c_w, hw_bf, NWORD / 16,
        h_topic, Wbf_t, c_t, ht_bf, NTOPIC / 16);

    gather<<<(NOUT * 64 + 255) / 256, 256, 0, stream>>>(offs, se, hw_bf, ht_bf, out);
}